// Round 1
// baseline (181.675 us; speedup 1.0000x reference)
//
#include <hip/hip_runtime.h>
#include <math.h>

// Problem constants
#define PCK_STRIDE 416      // packed row length
#define N_SAMPLES  32768
#define FFT_M      16384    // complex FFT size (real packing)
#define B_EVENTS   128
#define N_GROUPS   16

__device__ __constant__ const float NYQ_F  = 11025.0f;
#define PI_F 3.14159265358979323846f

__device__ inline float filt_at(const float* __restrict__ f, int k) {
    // linear interp of 16 control points to 16384 bins; bin 16384 is the zero pad
    if (k >= FFT_M) return 0.0f;
    float c = ((float)k + 0.5f) * (1.0f / 1024.0f) - 0.5f;
    c = fminf(fmaxf(c, 0.0f), 15.0f);
    int i0 = (int)floorf(c);
    int i1 = min(i0 + 1, 15);
    float w = c - (float)i0;
    return f[i0] * (1.0f - w) + f[i1] * w;
}

// ---------------- K1: softmax-f0, radians, decay scan ----------------
__global__ __launch_bounds__(128) void prep_kernel(
    const float* __restrict__ packed, const float* __restrict__ freqs,
    float* __restrict__ rW, float* __restrict__ res)
{
    const int b = blockIdx.x;
    const int t = threadIdx.x;
    __shared__ float sm[128];
    __shared__ float s_amp[128];
    const float* row = packed + b * PCK_STRIDE;
    float lv = row[t];
    s_amp[t] = row[256 + t] * 2.0f - 1.0f;
    sm[t] = lv; __syncthreads();
    for (int s = 64; s > 0; s >>= 1) { if (t < s) sm[t] = fmaxf(sm[t], sm[t + s]); __syncthreads(); }
    float mx = sm[0]; __syncthreads();
    float ex = __expf(lv - mx);
    sm[t] = ex; __syncthreads();
    for (int s = 64; s > 0; s >>= 1) { if (t < s) sm[t] += sm[t + s]; __syncthreads(); }
    float den = sm[0]; __syncthreads();
    sm[t] = ex * freqs[t]; __syncthreads();
    for (int s = 64; s > 0; s >>= 1) { if (t < s) sm[t] += sm[t + s]; __syncthreads(); }
    float num = sm[0];

    if (t < 8) {
        const float MIN_F0 = 40.0f / 11025.0f;
        const float F0_SPAN = 3000.0f / 11025.0f - 40.0f / 11025.0f;
        float f0s = num / den;
        float f0 = MIN_F0 + f0s * f0s * NYQ_F * F0_SPAN;
        float r = f0 * (float)(t + 1) * (PI_F / NYQ_F);
        if (r >= PI_F) r = 0.0f;
        rW[b * 8 + t] = r;
        float ha = row[384 + t];                 // harm_amp
        float hd = 0.5f + row[392 + t] * 0.5f;   // harm_decay
        float cur = 0.0f;
        float* rr = res + (b * 8 + t) * 128;
        for (int f = 0; f < 128; ++f) {
            float c = fmaxf(cur + s_amp[f] * ha, 0.0f);
            rr[f] = c;
            cur = c * hd;
        }
    }
}

// ---------------- K2: per-batch 16384-pt complex FFT filter in LDS ----------------
// real-pack x[2j]+i*x[2j+1]; DIF forward (natural->bitrev), pointwise
// untangle*H*retangle in bitrev domain, DIT inverse (bitrev->natural).
__global__ __launch_bounds__(512) void fft_filter_kernel(
    const float* __restrict__ noise, const float* __restrict__ packed,
    const float* __restrict__ gamp, float* __restrict__ noise_out)
{
    extern __shared__ float smem[];
    float* re = smem;
    float* im = smem + FFT_M;
    float* filt = smem + 2 * FFT_M;
    const int b = blockIdx.x;
    const int tid = threadIdx.x;
    const float g = gamp[0];

    const float2* nz = (const float2*)(noise + (size_t)b * N_SAMPLES);
    for (int j = tid; j < FFT_M; j += 512) {
        float2 v = nz[j];
        re[j] = v.x * g;
        im[j] = v.y * g;
    }
    if (tid < 16) filt[tid] = packed[b * PCK_STRIDE + 400 + tid];
    __syncthreads();

    // forward DIF: X[k] ends at position brev14(k)
    for (int half = FFT_M >> 1; half >= 1; half >>= 1) {
        const float ang = -6.283185307179586f / (float)(half << 1);
        for (int q = tid; q < (FFT_M >> 1); q += 512) {
            int t = q & (half - 1);
            int i = ((q & ~(half - 1)) << 1) | t;
            int jj = i + half;
            float ur = re[i], ui = im[i];
            float vr = re[jj], vi = im[jj];
            float s, c; __sincosf(ang * (float)t, &s, &c);
            re[i] = ur + vr; im[i] = ui + vi;
            float dr = ur - vr, di = ui - vi;
            re[jj] = dr * c - di * s;
            im[jj] = dr * s + di * c;
        }
        __syncthreads();
    }

    // pointwise: Y = X*H, rebuild packed spectrum Zw (bitrev positions), scale 1/M
    const float invM = 1.0f / (float)FFT_M;
    for (int k = tid; k <= (FFT_M >> 1); k += 512) {
        if (k == 0) {
            float z0r = re[0], z0i = im[0];
            float X0 = z0r + z0i;          // DC (real); Nyquist term is H[M]*X[M] = 0
            float y = 0.5f * filt_at(filt, 0) * X0 * invM;
            re[0] = y; im[0] = y;
        } else {
            int kq = FFT_M - k;
            int pk = (int)(__brev((unsigned)k) >> 18);
            int pq = (int)(__brev((unsigned)kq) >> 18);
            float zkr = re[pk], zki = im[pk];
            float zqr = re[pq], zqi = im[pq];
            float Er = 0.5f * (zkr + zqr), Ei = 0.5f * (zki - zqi);
            float Or = 0.5f * (zki + zqi), Oi = 0.5f * (zqr - zkr);
            float th = (float)k * (PI_F / (float)FFT_M);   // theta = pi*k/M
            float s, c; __sincosf(th, &s, &c);
            float ts = -s;                                  // t_k = (c, ts)
            float tOr = c * Or - ts * Oi;
            float tOi = c * Oi + ts * Or;
            float Hk = filt_at(filt, k);
            float Hq = filt_at(filt, kq);
            float Ykr = Hk * (Er + tOr), Yki = Hk * (Ei + tOi);   // Y[k]
            float Cr  = Hq * (Er - tOr), Ci  = Hq * (Ei - tOi);   // conj(Y[M-k])
            float Ar = 0.5f * (Ykr + Cr), Ai = 0.5f * (Yki + Ci);
            float Br = 0.5f * (Ykr - Cr), Bi = 0.5f * (Yki - Ci);
            float wkr = Ar + ts * Br - c * Bi;
            float wki = Ai + c * Br + ts * Bi;
            float wqr = Ar + c * Bi - ts * Br;
            float wqi = -Ai + c * Br + ts * Bi;
            re[pk] = wkr * invM; im[pk] = wki * invM;
            re[pq] = wqr * invM; im[pq] = wqi * invM;
        }
    }
    __syncthreads();

    // inverse DIT (bitrev in -> natural out), twiddle e^{+i...}, no scale (folded above)
    for (int half = 1; half <= (FFT_M >> 1); half <<= 1) {
        const float ang = 6.283185307179586f / (float)(half << 1);
        for (int q = tid; q < (FFT_M >> 1); q += 512) {
            int t = q & (half - 1);
            int i = ((q & ~(half - 1)) << 1) | t;
            int jj = i + half;
            float s, c; __sincosf(ang * (float)t, &s, &c);
            float xr = re[jj], xi = im[jj];
            float vr = xr * c - xi * s;
            float vi = xr * s + xi * c;
            float ur = re[i], ui = im[i];
            re[i] = ur + vr; im[i] = ui + vi;
            re[jj] = ur - vr; im[jj] = ui - vi;
        }
        __syncthreads();
    }

    float2* oz = (float2*)(noise_out + (size_t)b * N_SAMPLES);
    for (int j = tid; j < FFT_M; j += 512) {
        oz[j] = make_float2(re[j], im[j]);
    }
}

// ---------------- K3: gate noise, add harmonic bank, sum 8 events ----------------
__global__ __launch_bounds__(256) void assemble_kernel(
    const float* __restrict__ packed, const float* __restrict__ rW,
    const float* __restrict__ res, const float* __restrict__ noise_out,
    const float* __restrict__ oamp, float* __restrict__ out)
{
    const int g = blockIdx.y;
    const int chunk = blockIdx.x;
    const int tid = threadIdx.x;
    const int n = chunk * 256 + tid;
    const int fb = chunk - 1;   // frames fb..fb+2 cover all i0/i1 in this chunk

    __shared__ float s_res[8][8][3];
    __shared__ float s_ampf[8][3];
    __shared__ float s_r[8][8];
    if (tid < 192) {
        int e = tid / 24, rem = tid % 24, h = rem / 3, j = rem % 3;
        int f = min(max(fb + j, 0), 127);
        s_res[e][h][j] = res[((g * 8 + e) * 8 + h) * 128 + f];
    }
    if (tid < 24) {
        int e = tid / 3, j = tid % 3;
        int f = min(max(fb + j, 0), 127);
        s_ampf[e][j] = packed[(g * 8 + e) * PCK_STRIDE + 256 + f] * 2.0f - 1.0f;
    }
    if (tid >= 192 && tid < 256) {
        int u = tid - 192;
        s_r[u / 8][u % 8] = rW[g * 64 + u];
    }
    __syncthreads();

    float coords = ((float)n + 0.5f) * (1.0f / 256.0f) - 0.5f;
    coords = fminf(fmaxf(coords, 0.0f), 127.0f);
    int i0 = (int)floorf(coords);
    float w = coords - (float)i0;
    int j0 = i0 - fb;          // in {0,1}; clamped frames staged at j=0..2
    float osc50 = oamp[0];
    float pn = (float)(n + 1);
    float wm = 1.0f - w;

    float acc = 0.0f;
    for (int e = 0; e < 8; ++e) {
        int b = g * 8 + e;
        float nv = noise_out[(size_t)b * N_SAMPLES + n];
        float av = s_ampf[e][j0] * wm + s_ampf[e][j0 + 1] * w;
        float gate = (av >= 0.0f) ? av : 0.2f * av;
        acc += nv * gate;
        for (int h = 0; h < 8; ++h) {
            float rsv = s_res[e][h][j0] * wm + s_res[e][h][j0 + 1] * w;
            acc += rsv * osc50 * __sinf(pn * s_r[e][h]);
        }
    }
    out[(size_t)g * N_SAMPLES + n] = acc;
}

extern "C" void kernel_launch(void* const* d_in, const int* in_sizes, int n_in,
                              void* d_out, int out_size, void* d_ws, size_t ws_size,
                              hipStream_t stream) {
    const float* packed = (const float*)d_in[0];
    const float* freqs  = (const float*)d_in[1];
    const float* gamp   = (const float*)d_in[2];
    const float* oamp   = (const float*)d_in[3];
    const float* noise  = (const float*)d_in[4];
    float* out = (float*)d_out;

    float* ws = (float*)d_ws;
    float* noise_out = ws;                                   // 128*32768 floats (16 MB)
    float* res = ws + (size_t)B_EVENTS * N_SAMPLES;          // 128*8*128 floats
    float* rW  = res + B_EVENTS * 8 * 128;                   // 128*8 floats

    prep_kernel<<<B_EVENTS, 128, 0, stream>>>(packed, freqs, rW, res);
    fft_filter_kernel<<<B_EVENTS, 512, (2 * FFT_M + 16) * sizeof(float), stream>>>(
        noise, packed, gamp, noise_out);
    assemble_kernel<<<dim3(N_SAMPLES / 256, N_GROUPS), 256, 0, stream>>>(
        packed, rW, res, noise_out, oamp, out);
}

// Round 2
// 147.289 us; speedup vs baseline: 1.2335x; 1.2335x over previous
//
#include <hip/hip_runtime.h>
#include <math.h>

#define PCK_STRIDE 416
#define N_SAMPLES  32768
#define FFT_M      16384        // complex FFT size (real packing)
#define B_EVENTS   128
#define N_GROUPS   16
#define PI_F 3.14159265358979323846f

// LDS padded mapping: +1 float per 32-block breaks same-bank aliasing for
// the register-phase contiguous 32-element loads (bank = (tid+j)%32).
#define MAP(i) ((i) + ((i) >> 5))
#define LDS_N  16896            // 16384 + 512 pad

__device__ inline float filt_at(const float* __restrict__ f, int k) {
    if (k >= FFT_M) return 0.0f;
    float c = ((float)k + 0.5f) * (1.0f / 1024.0f) - 0.5f;
    c = fminf(fmaxf(c, 0.0f), 15.0f);
    int i0 = (int)floorf(c);
    int i1 = min(i0 + 1, 15);
    float w = c - (float)i0;
    return f[i0] * (1.0f - w) + f[i1] * w;
}

// ---------------- K1: softmax-f0, radians, decay scan ----------------
__global__ __launch_bounds__(128) void prep_kernel(
    const float* __restrict__ packed, const float* __restrict__ freqs,
    float* __restrict__ rW, float* __restrict__ res)
{
    const int b = blockIdx.x;
    const int t = threadIdx.x;
    __shared__ float sm[128];
    __shared__ float s_amp[128];
    const float* row = packed + b * PCK_STRIDE;
    float lv = row[t];
    s_amp[t] = row[256 + t] * 2.0f - 1.0f;
    sm[t] = lv; __syncthreads();
    for (int s = 64; s > 0; s >>= 1) { if (t < s) sm[t] = fmaxf(sm[t], sm[t + s]); __syncthreads(); }
    float mx = sm[0]; __syncthreads();
    float ex = __expf(lv - mx);
    sm[t] = ex; __syncthreads();
    for (int s = 64; s > 0; s >>= 1) { if (t < s) sm[t] += sm[t + s]; __syncthreads(); }
    float den = sm[0]; __syncthreads();
    sm[t] = ex * freqs[t]; __syncthreads();
    for (int s = 64; s > 0; s >>= 1) { if (t < s) sm[t] += sm[t + s]; __syncthreads(); }
    float num = sm[0];

    if (t < 8) {
        const float MIN_F0 = 40.0f / 11025.0f;
        const float F0_SPAN = 3000.0f / 11025.0f - 40.0f / 11025.0f;
        float f0s = num / den;
        float f0 = MIN_F0 + f0s * f0s * 11025.0f * F0_SPAN;
        float r = f0 * (float)(t + 1) * (PI_F / 11025.0f);
        if (r >= PI_F) r = 0.0f;
        rW[b * 8 + t] = r;
        float ha = row[384 + t];
        float hd = 0.5f + row[392 + t] * 0.5f;
        float cur = 0.0f;
        float* rr = res + (b * 8 + t) * 128;
        for (int f = 0; f < 128; ++f) {
            float c = fmaxf(cur + s_amp[f] * ha, 0.0f);
            rr[f] = c;
            cur = c * hd;
        }
    }
}

// ---------------- radix-4 LDS stages ----------------
// DIF: y0=(a+c)+(b+d); y1=[(a+c)-(b+d)]w2; y2=w1[(a-c)-i(b-d)]; y3=w3[(a-c)+i(b-d)]
template<int L>
__device__ inline void r4_dif_stage(float* re, float* im, int tid) {
    constexpr int q = L >> 2;
    constexpr float ang = -6.28318530717958647692f / (float)L;
    #pragma unroll
    for (int s = 0; s < 8; ++s) {
        int m = tid + (s << 9);
        int t = m & (q - 1);
        int i0 = ((m & ~(q - 1)) << 2) | t;
        int ia = MAP(i0), ib = MAP(i0 + q), ic = MAP(i0 + 2 * q), id = MAP(i0 + 3 * q);
        float ar = re[ia], ai = im[ia];
        float br = re[ib], bi = im[ib];
        float cr = re[ic], ci = im[ic];
        float dr = re[id], di = im[id];
        float s1, c1; __sincosf(ang * (float)t, &s1, &c1);
        float c2 = c1 * c1 - s1 * s1, s2 = 2.0f * c1 * s1;
        float c3 = c2 * c1 - s2 * s1, s3 = c2 * s1 + s2 * c1;
        float s0r = ar + cr, s0i = ai + ci;
        float t1r = br + dr, t1i = bi + di;
        float d0r = ar - cr, d0i = ai - ci;
        float d1r = br - dr, d1i = bi - di;
        re[ia] = s0r + t1r; im[ia] = s0i + t1i;
        float er = s0r - t1r, ei = s0i - t1i;
        re[ib] = er * c2 - ei * s2; im[ib] = er * s2 + ei * c2;
        float fr = d0r + d1i, fi = d0i - d1r;   // (a-c) - i(b-d)
        re[ic] = fr * c1 - fi * s1; im[ic] = fr * s1 + fi * c1;
        float gr = d0r - d1i, gi = d0i + d1r;   // (a-c) + i(b-d)
        re[id] = gr * c3 - gi * s3; im[id] = gr * s3 + gi * c3;
    }
    __syncthreads();
}

// DIT: tb=b*w2; td=d*w2; B0=a+tb B1=a-tb B2=c+td B3=c-td;
// t0=B2*w1; t1=B3*(i*w1); y0=B0+t0 y1=B1+t1 y2=B0-t0 y3=B1-t1
template<int L>
__device__ inline void r4_dit_stage(float* re, float* im, int tid) {
    constexpr int q = L >> 2;
    constexpr float ang = 6.28318530717958647692f / (float)L;
    #pragma unroll
    for (int s = 0; s < 8; ++s) {
        int m = tid + (s << 9);
        int t = m & (q - 1);
        int i0 = ((m & ~(q - 1)) << 2) | t;
        int ia = MAP(i0), ib = MAP(i0 + q), ic = MAP(i0 + 2 * q), id = MAP(i0 + 3 * q);
        float ar = re[ia], ai = im[ia];
        float br = re[ib], bi = im[ib];
        float cr = re[ic], ci = im[ic];
        float dr = re[id], di = im[id];
        float s1, c1; __sincosf(ang * (float)t, &s1, &c1);
        float c2 = c1 * c1 - s1 * s1, s2 = 2.0f * c1 * s1;
        float tbr = br * c2 - bi * s2, tbi = br * s2 + bi * c2;
        float tdr = dr * c2 - di * s2, tdi = dr * s2 + di * c2;
        float B0r = ar + tbr, B0i = ai + tbi;
        float B1r = ar - tbr, B1i = ai - tbi;
        float B2r = cr + tdr, B2i = ci + tdi;
        float B3r = cr - tdr, B3i = ci - tdi;
        float t0r = B2r * c1 - B2i * s1, t0i = B2r * s1 + B2i * c1;
        float t1r = -B3r * s1 - B3i * c1, t1i = B3r * c1 - B3i * s1;  // B3*(i*w1)
        re[ia] = B0r + t0r; im[ia] = B0i + t0i;
        re[ib] = B1r + t1r; im[ib] = B1i + t1i;
        re[ic] = B0r - t0r; im[ic] = B0i - t0i;
        re[id] = B1r - t1r; im[id] = B1i - t1i;
    }
    __syncthreads();
}

// ---------------- K2: 16384-pt complex FFT filter ----------------
__global__ __launch_bounds__(512) void fft_filter_kernel(
    const float* __restrict__ noise, const float* __restrict__ packed,
    const float* __restrict__ gamp, float* __restrict__ noise_out)
{
    extern __shared__ float smem[];
    float* re = smem;
    float* im = smem + LDS_N;
    float* filt = smem + 2 * LDS_N;
    const int b = blockIdx.x;
    const int tid = threadIdx.x;
    const float g = gamp[0];

    // twiddle table cos/sin(pi*k/16), compile-time folded in register stages
    constexpr float CT[16] = { 1.0f, 0.98078528f, 0.92387953f, 0.83146961f,
        0.70710678f, 0.55557023f, 0.38268343f, 0.19509032f, 0.0f, -0.19509032f,
        -0.38268343f, -0.55557023f, -0.70710678f, -0.83146961f, -0.92387953f, -0.98078528f };
    constexpr float ST[16] = { 0.0f, 0.19509032f, 0.38268343f, 0.55557023f,
        0.70710678f, 0.83146961f, 0.92387953f, 0.98078528f, 1.0f, 0.98078528f,
        0.92387953f, 0.83146961f, 0.70710678f, 0.55557023f, 0.38268343f, 0.19509032f };

    // --- load + fused r2 DIF (half=8192) ---
    const float2* nz = (const float2*)(noise + (size_t)b * N_SAMPLES);
    #pragma unroll
    for (int s = 0; s < 16; ++s) {
        int j = tid + (s << 9);
        float2 v0 = nz[j];
        float2 v1 = nz[j + 8192];
        float ur = v0.x * g, ui = v0.y * g;
        float wr = v1.x * g, wi = v1.y * g;
        float s1, c1; __sincosf((-PI_F / 8192.0f) * (float)j, &s1, &c1);
        int a0 = MAP(j), a1 = MAP(j + 8192);
        re[a0] = ur + wr; im[a0] = ui + wi;
        float dr = ur - wr, di = ui - wi;
        re[a1] = dr * c1 - di * s1;
        im[a1] = dr * s1 + di * c1;
    }
    if (tid < 16) filt[tid] = packed[b * PCK_STRIDE + 400 + tid];
    __syncthreads();

    // --- radix-4 DIF stages down to 32-blocks ---
    r4_dif_stage<8192>(re, im, tid);
    r4_dif_stage<2048>(re, im, tid);
    r4_dif_stage<512>(re, im, tid);
    r4_dif_stage<128>(re, im, tid);

    // --- register 32-point DIF (half = 16,8,4,2,1) ---
    {
        float vr[32], vi[32];
        int base = 33 * tid;    // MAP(32*tid + j) = 33*tid + j
        #pragma unroll
        for (int j = 0; j < 32; ++j) { vr[j] = re[base + j]; vi[j] = im[base + j]; }
        #pragma unroll
        for (int e = 0; e < 5; ++e) {
            const int h = 16 >> e;
            #pragma unroll
            for (int blk = 0; blk < 32; blk += 2 * h) {
                #pragma unroll
                for (int t = 0; t < h; ++t) {
                    int i = blk + t, j2 = i + h;
                    int k = t * (16 / h);
                    float c = CT[k], s = -ST[k];
                    float ur = vr[i], ui = vi[i];
                    float wr = vr[j2], wi = vi[j2];
                    vr[i] = ur + wr; vi[i] = ui + wi;
                    float dr = ur - wr, di = ui - wi;
                    vr[j2] = dr * c - di * s;
                    vi[j2] = dr * s + di * c;
                }
            }
        }
        #pragma unroll
        for (int j = 0; j < 32; ++j) { re[base + j] = vr[j]; im[base + j] = vi[j]; }
    }
    __syncthreads();

    // --- pointwise untangle * H * retangle, bitrev domain, natural-pos enum ---
    const float invM = 1.0f / (float)FFT_M;
    #pragma unroll
    for (int s = 0; s < 16; ++s) {
        int jj = (tid + (s << 9)) << 1;       // even position
        if (jj == 0) {
            int p0 = MAP(0);
            float z0r = re[p0], z0i = im[p0];
            float y = 0.5f * filt_at(filt, 0) * (z0r + z0i) * invM;
            re[p0] = y; im[p0] = y;
            int p1 = MAP(1);                  // k=8192 self-pair at brev(8192)=1
            float H = filt_at(filt, 8192) * invM;
            re[p1] *= H; im[p1] *= H;
        } else {
            int k = (int)(__brev((unsigned)jj) >> 18);     // k in [1,8192)
            int kq = FFT_M - k;
            int pk = MAP(jj);
            int pq = MAP((int)(__brev((unsigned)kq) >> 18));
            float zkr = re[pk], zki = im[pk];
            float zqr = re[pq], zqi = im[pq];
            float Er = 0.5f * (zkr + zqr), Ei = 0.5f * (zki - zqi);
            float Or = 0.5f * (zki + zqi), Oi = 0.5f * (zqr - zkr);
            float th = (float)k * (PI_F / (float)FFT_M);
            float s1, c1; __sincosf(th, &s1, &c1);
            float ts = -s1;
            float tOr = c1 * Or - ts * Oi;
            float tOi = c1 * Oi + ts * Or;
            float Hk = filt_at(filt, k);
            float Hq = filt_at(filt, kq);
            float Ykr = Hk * (Er + tOr), Yki = Hk * (Ei + tOi);
            float Cr  = Hq * (Er - tOr), Ci  = Hq * (Ei - tOi);
            float Ar = 0.5f * (Ykr + Cr), Ai = 0.5f * (Yki + Ci);
            float Br = 0.5f * (Ykr - Cr), Bi = 0.5f * (Yki - Ci);
            re[pk] = (Ar + ts * Br - c1 * Bi) * invM;
            im[pk] = (Ai + c1 * Br + ts * Bi) * invM;
            re[pq] = (Ar + c1 * Bi - ts * Br) * invM;
            im[pq] = (-Ai + c1 * Br + ts * Bi) * invM;
        }
    }
    __syncthreads();

    // --- register 32-point DIT (half = 1,2,4,8,16) ---
    {
        float vr[32], vi[32];
        int base = 33 * tid;
        #pragma unroll
        for (int j = 0; j < 32; ++j) { vr[j] = re[base + j]; vi[j] = im[base + j]; }
        #pragma unroll
        for (int e = 0; e < 5; ++e) {
            const int h = 1 << e;
            #pragma unroll
            for (int blk = 0; blk < 32; blk += 2 * h) {
                #pragma unroll
                for (int t = 0; t < h; ++t) {
                    int i = blk + t, j2 = i + h;
                    int k = t * (16 / h);
                    float c = CT[k], s = ST[k];
                    float xr = vr[j2], xi = vi[j2];
                    float wr = xr * c - xi * s, wi = xr * s + xi * c;
                    float ur = vr[i], ui = vi[i];
                    vr[i] = ur + wr; vi[i] = ui + wi;
                    vr[j2] = ur - wr; vi[j2] = ui - wi;
                }
            }
        }
        #pragma unroll
        for (int j = 0; j < 32; ++j) { re[base + j] = vr[j]; im[base + j] = vi[j]; }
    }
    __syncthreads();

    // --- radix-4 DIT stages ---
    r4_dit_stage<128>(re, im, tid);
    r4_dit_stage<512>(re, im, tid);
    r4_dit_stage<2048>(re, im, tid);
    r4_dit_stage<8192>(re, im, tid);

    // --- fused final r2 DIT (half=8192) + store ---
    float2* oz = (float2*)(noise_out + (size_t)b * N_SAMPLES);
    #pragma unroll
    for (int s = 0; s < 16; ++s) {
        int j = tid + (s << 9);
        int a0 = MAP(j), a1 = MAP(j + 8192);
        float ur = re[a0], ui = im[a0];
        float xr = re[a1], xi = im[a1];
        float s1, c1; __sincosf((PI_F / 8192.0f) * (float)j, &s1, &c1);
        float wr = xr * c1 - xi * s1, wi = xr * s1 + xi * c1;
        oz[j] = make_float2(ur + wr, ui + wi);
        oz[j + 8192] = make_float2(ur - wr, ui - wi);
    }
}

// ---------------- K3: gate noise, add harmonic bank, sum 8 events ----------------
__global__ __launch_bounds__(256) void assemble_kernel(
    const float* __restrict__ packed, const float* __restrict__ rW,
    const float* __restrict__ res, const float* __restrict__ noise_out,
    const float* __restrict__ oamp, float* __restrict__ out)
{
    const int g = blockIdx.y;
    const int chunk = blockIdx.x;
    const int tid = threadIdx.x;
    const int n = chunk * 256 + tid;
    const int fb = chunk - 1;

    __shared__ float s_res[8][8][3];
    __shared__ float s_ampf[8][3];
    __shared__ float s_r[8][8];
    if (tid < 192) {
        int e = tid / 24, rem = tid % 24, h = rem / 3, j = rem % 3;
        int f = min(max(fb + j, 0), 127);
        s_res[e][h][j] = res[((g * 8 + e) * 8 + h) * 128 + f];
    }
    if (tid < 24) {
        int e = tid / 3, j = tid % 3;
        int f = min(max(fb + j, 0), 127);
        s_ampf[e][j] = packed[(g * 8 + e) * PCK_STRIDE + 256 + f] * 2.0f - 1.0f;
    }
    if (tid >= 192 && tid < 256) {
        int u = tid - 192;
        s_r[u / 8][u % 8] = rW[g * 64 + u];
    }
    __syncthreads();

    float coords = ((float)n + 0.5f) * (1.0f / 256.0f) - 0.5f;
    coords = fminf(fmaxf(coords, 0.0f), 127.0f);
    int i0 = (int)floorf(coords);
    float w = coords - (float)i0;
    int j0 = i0 - fb;
    float osc50 = oamp[0];
    float pn = (float)(n + 1);
    float wm = 1.0f - w;

    float acc = 0.0f;
    for (int e = 0; e < 8; ++e) {
        int b = g * 8 + e;
        float nv = noise_out[(size_t)b * N_SAMPLES + n];
        float av = s_ampf[e][j0] * wm + s_ampf[e][j0 + 1] * w;
        float gate = (av >= 0.0f) ? av : 0.2f * av;
        acc += nv * gate;
        for (int h = 0; h < 8; ++h) {
            float rsv = s_res[e][h][j0] * wm + s_res[e][h][j0 + 1] * w;
            acc += rsv * osc50 * __sinf(pn * s_r[e][h]);
        }
    }
    out[(size_t)g * N_SAMPLES + n] = acc;
}

extern "C" void kernel_launch(void* const* d_in, const int* in_sizes, int n_in,
                              void* d_out, int out_size, void* d_ws, size_t ws_size,
                              hipStream_t stream) {
    const float* packed = (const float*)d_in[0];
    const float* freqs  = (const float*)d_in[1];
    const float* gamp   = (const float*)d_in[2];
    const float* oamp   = (const float*)d_in[3];
    const float* noise  = (const float*)d_in[4];
    float* out = (float*)d_out;

    float* ws = (float*)d_ws;
    float* noise_out = ws;
    float* res = ws + (size_t)B_EVENTS * N_SAMPLES;
    float* rW  = res + B_EVENTS * 8 * 128;

    prep_kernel<<<B_EVENTS, 128, 0, stream>>>(packed, freqs, rW, res);
    fft_filter_kernel<<<B_EVENTS, 512, (2 * LDS_N + 16) * sizeof(float), stream>>>(
        noise, packed, gamp, noise_out);
    assemble_kernel<<<dim3(N_SAMPLES / 256, N_GROUPS), 256, 0, stream>>>(
        packed, rW, res, noise_out, oamp, out);
}

// Round 3
// 145.024 us; speedup vs baseline: 1.2527x; 1.0156x over previous
//
#include <hip/hip_runtime.h>
#include <math.h>

#define PCK_STRIDE 416
#define N_SAMPLES  32768
#define FFT_M      16384        // complex FFT size (real packing)
#define B_EVENTS   128
#define N_GROUPS   16
#define PI_F 3.14159265358979323846f

// LDS padded mapping: +1 float per 32-block breaks same-bank aliasing for
// the register-phase contiguous 32-element loads (bank = (tid+j)%32).
#define MAP(i) ((i) + ((i) >> 5))
#define LDS_N  16896            // 16384 + 512 pad

__device__ inline float filt_at(const float* __restrict__ f, int k) {
    if (k >= FFT_M) return 0.0f;
    float c = ((float)k + 0.5f) * (1.0f / 1024.0f) - 0.5f;
    c = fminf(fmaxf(c, 0.0f), 15.0f);
    int i0 = (int)floorf(c);
    int i1 = min(i0 + 1, 15);
    float w = c - (float)i0;
    return f[i0] * (1.0f - w) + f[i1] * w;
}

// ---------------- K1: softmax-f0, radians, decay scan ----------------
__global__ __launch_bounds__(128) void prep_kernel(
    const float* __restrict__ packed, const float* __restrict__ freqs,
    float* __restrict__ rW, float* __restrict__ res)
{
    const int b = blockIdx.x;
    const int t = threadIdx.x;
    __shared__ float sm[128];
    __shared__ float s_amp[128];
    const float* row = packed + b * PCK_STRIDE;
    float lv = row[t];
    s_amp[t] = row[256 + t] * 2.0f - 1.0f;
    sm[t] = lv; __syncthreads();
    for (int s = 64; s > 0; s >>= 1) { if (t < s) sm[t] = fmaxf(sm[t], sm[t + s]); __syncthreads(); }
    float mx = sm[0]; __syncthreads();
    float ex = __expf(lv - mx);
    sm[t] = ex; __syncthreads();
    for (int s = 64; s > 0; s >>= 1) { if (t < s) sm[t] += sm[t + s]; __syncthreads(); }
    float den = sm[0]; __syncthreads();
    sm[t] = ex * freqs[t]; __syncthreads();
    for (int s = 64; s > 0; s >>= 1) { if (t < s) sm[t] += sm[t + s]; __syncthreads(); }
    float num = sm[0];

    if (t < 8) {
        const float MIN_F0 = 40.0f / 11025.0f;
        const float F0_SPAN = 3000.0f / 11025.0f - 40.0f / 11025.0f;
        float f0s = num / den;
        float f0 = MIN_F0 + f0s * f0s * 11025.0f * F0_SPAN;
        float r = f0 * (float)(t + 1) * (PI_F / 11025.0f);
        if (r >= PI_F) r = 0.0f;
        rW[b * 8 + t] = r;
        float ha = row[384 + t];
        float hd = 0.5f + row[392 + t] * 0.5f;
        float cur = 0.0f;
        float* rr = res + (b * 8 + t) * 128;
        for (int f = 0; f < 128; ++f) {
            float c = fmaxf(cur + s_amp[f] * ha, 0.0f);
            rr[f] = c;
            cur = c * hd;
        }
    }
}

// ---------------- radix-4 LDS stages ----------------
template<int L>
__device__ inline void r4_dif_stage(float* re, float* im, int tid) {
    constexpr int q = L >> 2;
    constexpr float ang = -6.28318530717958647692f / (float)L;
    #pragma unroll
    for (int s = 0; s < 8; ++s) {
        int m = tid + (s << 9);
        int t = m & (q - 1);
        int i0 = ((m & ~(q - 1)) << 2) | t;
        int ia = MAP(i0), ib = MAP(i0 + q), ic = MAP(i0 + 2 * q), id = MAP(i0 + 3 * q);
        float ar = re[ia], ai = im[ia];
        float br = re[ib], bi = im[ib];
        float cr = re[ic], ci = im[ic];
        float dr = re[id], di = im[id];
        float s1, c1; __sincosf(ang * (float)t, &s1, &c1);
        float c2 = c1 * c1 - s1 * s1, s2 = 2.0f * c1 * s1;
        float c3 = c2 * c1 - s2 * s1, s3 = c2 * s1 + s2 * c1;
        float s0r = ar + cr, s0i = ai + ci;
        float t1r = br + dr, t1i = bi + di;
        float d0r = ar - cr, d0i = ai - ci;
        float d1r = br - dr, d1i = bi - di;
        re[ia] = s0r + t1r; im[ia] = s0i + t1i;
        float er = s0r - t1r, ei = s0i - t1i;
        re[ib] = er * c2 - ei * s2; im[ib] = er * s2 + ei * c2;
        float fr = d0r + d1i, fi = d0i - d1r;   // (a-c) - i(b-d)
        re[ic] = fr * c1 - fi * s1; im[ic] = fr * s1 + fi * c1;
        float gr = d0r - d1i, gi = d0i + d1r;   // (a-c) + i(b-d)
        re[id] = gr * c3 - gi * s3; im[id] = gr * s3 + gi * c3;
    }
    __syncthreads();
}

template<int L>
__device__ inline void r4_dit_stage(float* re, float* im, int tid) {
    constexpr int q = L >> 2;
    constexpr float ang = 6.28318530717958647692f / (float)L;
    #pragma unroll
    for (int s = 0; s < 8; ++s) {
        int m = tid + (s << 9);
        int t = m & (q - 1);
        int i0 = ((m & ~(q - 1)) << 2) | t;
        int ia = MAP(i0), ib = MAP(i0 + q), ic = MAP(i0 + 2 * q), id = MAP(i0 + 3 * q);
        float ar = re[ia], ai = im[ia];
        float br = re[ib], bi = im[ib];
        float cr = re[ic], ci = im[ic];
        float dr = re[id], di = im[id];
        float s1, c1; __sincosf(ang * (float)t, &s1, &c1);
        float c2 = c1 * c1 - s1 * s1, s2 = 2.0f * c1 * s1;
        float tbr = br * c2 - bi * s2, tbi = br * s2 + bi * c2;
        float tdr = dr * c2 - di * s2, tdi = dr * s2 + di * c2;
        float B0r = ar + tbr, B0i = ai + tbi;
        float B1r = ar - tbr, B1i = ai - tbi;
        float B2r = cr + tdr, B2i = ci + tdi;
        float B3r = cr - tdr, B3i = ci - tdi;
        float t0r = B2r * c1 - B2i * s1, t0i = B2r * s1 + B2i * c1;
        float t1r = -B3r * s1 - B3i * c1, t1i = B3r * c1 - B3i * s1;  // B3*(i*w1)
        re[ia] = B0r + t0r; im[ia] = B0i + t0i;
        re[ib] = B1r + t1r; im[ib] = B1i + t1i;
        re[ic] = B0r - t0r; im[ic] = B0i - t0i;
        re[id] = B1r - t1r; im[id] = B1i - t1i;
    }
    __syncthreads();
}

// ---------------- K2: 16384-pt complex FFT filter ----------------
// __launch_bounds__(512, 2): 8 waves/block = 2 waves/EU -> VGPR cap 256, so
// the register 32-point phases (64 live floats) do NOT spill to scratch.
// LDS (132 KB) already limits to 1 block/CU, so this costs no occupancy.
__global__ __launch_bounds__(512, 2) void fft_filter_kernel(
    const float* __restrict__ noise, const float* __restrict__ packed,
    const float* __restrict__ gamp, float* __restrict__ noise_out)
{
    extern __shared__ float smem[];
    float* re = smem;
    float* im = smem + LDS_N;
    float* filt = smem + 2 * LDS_N;
    const int b = blockIdx.x;
    const int tid = threadIdx.x;
    const float g = gamp[0];

    constexpr float CT[16] = { 1.0f, 0.98078528f, 0.92387953f, 0.83146961f,
        0.70710678f, 0.55557023f, 0.38268343f, 0.19509032f, 0.0f, -0.19509032f,
        -0.38268343f, -0.55557023f, -0.70710678f, -0.83146961f, -0.92387953f, -0.98078528f };
    constexpr float ST[16] = { 0.0f, 0.19509032f, 0.38268343f, 0.55557023f,
        0.70710678f, 0.83146961f, 0.92387953f, 0.98078528f, 1.0f, 0.98078528f,
        0.92387953f, 0.83146961f, 0.70710678f, 0.55557023f, 0.38268343f, 0.19509032f };

    // --- load + fused r2 DIF (half=8192) ---
    const float2* nz = (const float2*)(noise + (size_t)b * N_SAMPLES);
    #pragma unroll
    for (int s = 0; s < 16; ++s) {
        int j = tid + (s << 9);
        float2 v0 = nz[j];
        float2 v1 = nz[j + 8192];
        float ur = v0.x * g, ui = v0.y * g;
        float wr = v1.x * g, wi = v1.y * g;
        float s1, c1; __sincosf((-PI_F / 8192.0f) * (float)j, &s1, &c1);
        int a0 = MAP(j), a1 = MAP(j + 8192);
        re[a0] = ur + wr; im[a0] = ui + wi;
        float dr = ur - wr, di = ui - wi;
        re[a1] = dr * c1 - di * s1;
        im[a1] = dr * s1 + di * c1;
    }
    if (tid < 16) filt[tid] = packed[b * PCK_STRIDE + 400 + tid];
    __syncthreads();

    // --- radix-4 DIF stages down to 32-blocks ---
    r4_dif_stage<8192>(re, im, tid);
    r4_dif_stage<2048>(re, im, tid);
    r4_dif_stage<512>(re, im, tid);
    r4_dif_stage<128>(re, im, tid);

    // --- register 32-point DIF (half = 16,8,4,2,1) ---
    {
        float vr[32], vi[32];
        int base = 33 * tid;    // MAP(32*tid + j) = 33*tid + j
        #pragma unroll
        for (int j = 0; j < 32; ++j) { vr[j] = re[base + j]; vi[j] = im[base + j]; }
        #pragma unroll
        for (int e = 0; e < 5; ++e) {
            const int h = 16 >> e;
            #pragma unroll
            for (int blk = 0; blk < 32; blk += 2 * h) {
                #pragma unroll
                for (int t = 0; t < h; ++t) {
                    int i = blk + t, j2 = i + h;
                    int k = t * (16 / h);
                    float c = CT[k], s = -ST[k];
                    float ur = vr[i], ui = vi[i];
                    float wr = vr[j2], wi = vi[j2];
                    vr[i] = ur + wr; vi[i] = ui + wi;
                    float dr = ur - wr, di = ui - wi;
                    vr[j2] = dr * c - di * s;
                    vi[j2] = dr * s + di * c;
                }
            }
        }
        #pragma unroll
        for (int j = 0; j < 32; ++j) { re[base + j] = vr[j]; im[base + j] = vi[j]; }
    }
    __syncthreads();

    // --- pointwise untangle * H * retangle, bitrev domain, natural-pos enum ---
    const float invM = 1.0f / (float)FFT_M;
    #pragma unroll
    for (int s = 0; s < 16; ++s) {
        int jj = (tid + (s << 9)) << 1;       // even position
        if (jj == 0) {
            int p0 = MAP(0);
            float z0r = re[p0], z0i = im[p0];
            float y = 0.5f * filt_at(filt, 0) * (z0r + z0i) * invM;
            re[p0] = y; im[p0] = y;
            int p1 = MAP(1);                  // k=8192 self-pair at brev(8192)=1
            float H = filt_at(filt, 8192) * invM;
            re[p1] *= H; im[p1] *= H;
        } else {
            int k = (int)(__brev((unsigned)jj) >> 18);     // k in [1,8192)
            int kq = FFT_M - k;
            int pk = MAP(jj);
            int pq = MAP((int)(__brev((unsigned)kq) >> 18));
            float zkr = re[pk], zki = im[pk];
            float zqr = re[pq], zqi = im[pq];
            float Er = 0.5f * (zkr + zqr), Ei = 0.5f * (zki - zqi);
            float Or = 0.5f * (zki + zqi), Oi = 0.5f * (zqr - zkr);
            float th = (float)k * (PI_F / (float)FFT_M);
            float s1, c1; __sincosf(th, &s1, &c1);
            float ts = -s1;
            float tOr = c1 * Or - ts * Oi;
            float tOi = c1 * Oi + ts * Or;
            float Hk = filt_at(filt, k);
            float Hq = filt_at(filt, kq);
            float Ykr = Hk * (Er + tOr), Yki = Hk * (Ei + tOi);
            float Cr  = Hq * (Er - tOr), Ci  = Hq * (Ei - tOi);
            float Ar = 0.5f * (Ykr + Cr), Ai = 0.5f * (Yki + Ci);
            float Br = 0.5f * (Ykr - Cr), Bi = 0.5f * (Yki - Ci);
            re[pk] = (Ar + ts * Br - c1 * Bi) * invM;
            im[pk] = (Ai + c1 * Br + ts * Bi) * invM;
            re[pq] = (Ar + c1 * Bi - ts * Br) * invM;
            im[pq] = (-Ai + c1 * Br + ts * Bi) * invM;
        }
    }
    __syncthreads();

    // --- register 32-point DIT (half = 1,2,4,8,16) ---
    {
        float vr[32], vi[32];
        int base = 33 * tid;
        #pragma unroll
        for (int j = 0; j < 32; ++j) { vr[j] = re[base + j]; vi[j] = im[base + j]; }
        #pragma unroll
        for (int e = 0; e < 5; ++e) {
            const int h = 1 << e;
            #pragma unroll
            for (int blk = 0; blk < 32; blk += 2 * h) {
                #pragma unroll
                for (int t = 0; t < h; ++t) {
                    int i = blk + t, j2 = i + h;
                    int k = t * (16 / h);
                    float c = CT[k], s = ST[k];
                    float xr = vr[j2], xi = vi[j2];
                    float wr = xr * c - xi * s, wi = xr * s + xi * c;
                    float ur = vr[i], ui = vi[i];
                    vr[i] = ur + wr; vi[i] = ui + wi;
                    vr[j2] = ur - wr; vi[j2] = ui - wi;
                }
            }
        }
        #pragma unroll
        for (int j = 0; j < 32; ++j) { re[base + j] = vr[j]; im[base + j] = vi[j]; }
    }
    __syncthreads();

    // --- radix-4 DIT stages ---
    r4_dit_stage<128>(re, im, tid);
    r4_dit_stage<512>(re, im, tid);
    r4_dit_stage<2048>(re, im, tid);
    r4_dit_stage<8192>(re, im, tid);

    // --- fused final r2 DIT (half=8192) + store ---
    float2* oz = (float2*)(noise_out + (size_t)b * N_SAMPLES);
    #pragma unroll
    for (int s = 0; s < 16; ++s) {
        int j = tid + (s << 9);
        int a0 = MAP(j), a1 = MAP(j + 8192);
        float ur = re[a0], ui = im[a0];
        float xr = re[a1], xi = im[a1];
        float s1, c1; __sincosf((PI_F / 8192.0f) * (float)j, &s1, &c1);
        float wr = xr * c1 - xi * s1, wi = xr * s1 + xi * c1;
        oz[j] = make_float2(ur + wr, ui + wi);
        oz[j + 8192] = make_float2(ur - wr, ui - wi);
    }
}

// ---------------- K3: gate noise, add harmonic bank, sum 8 events ----------------
__global__ __launch_bounds__(256) void assemble_kernel(
    const float* __restrict__ packed, const float* __restrict__ rW,
    const float* __restrict__ res, const float* __restrict__ noise_out,
    const float* __restrict__ oamp, float* __restrict__ out)
{
    const int g = blockIdx.y;
    const int chunk = blockIdx.x;
    const int tid = threadIdx.x;
    const int n = chunk * 256 + tid;
    const int fb = chunk - 1;

    __shared__ float s_res[8][8][3];
    __shared__ float s_ampf[8][3];
    __shared__ float s_r[8][8];
    if (tid < 192) {
        int e = tid / 24, rem = tid % 24, h = rem / 3, j = rem % 3;
        int f = min(max(fb + j, 0), 127);
        s_res[e][h][j] = res[((g * 8 + e) * 8 + h) * 128 + f];
    }
    if (tid < 24) {
        int e = tid / 3, j = tid % 3;
        int f = min(max(fb + j, 0), 127);
        s_ampf[e][j] = packed[(g * 8 + e) * PCK_STRIDE + 256 + f] * 2.0f - 1.0f;
    }
    if (tid >= 192 && tid < 256) {
        int u = tid - 192;
        s_r[u / 8][u % 8] = rW[g * 64 + u];
    }
    __syncthreads();

    float coords = ((float)n + 0.5f) * (1.0f / 256.0f) - 0.5f;
    coords = fminf(fmaxf(coords, 0.0f), 127.0f);
    int i0 = (int)floorf(coords);
    float w = coords - (float)i0;
    int j0 = i0 - fb;
    float osc50 = oamp[0];
    float pn = (float)(n + 1);
    float wm = 1.0f - w;

    float acc = 0.0f;
    for (int e = 0; e < 8; ++e) {
        int b = g * 8 + e;
        float nv = noise_out[(size_t)b * N_SAMPLES + n];
        float av = s_ampf[e][j0] * wm + s_ampf[e][j0 + 1] * w;
        float gate = (av >= 0.0f) ? av : 0.2f * av;
        acc += nv * gate;
        for (int h = 0; h < 8; ++h) {
            float rsv = s_res[e][h][j0] * wm + s_res[e][h][j0 + 1] * w;
            acc += rsv * osc50 * __sinf(pn * s_r[e][h]);
        }
    }
    out[(size_t)g * N_SAMPLES + n] = acc;
}

extern "C" void kernel_launch(void* const* d_in, const int* in_sizes, int n_in,
                              void* d_out, int out_size, void* d_ws, size_t ws_size,
                              hipStream_t stream) {
    const float* packed = (const float*)d_in[0];
    const float* freqs  = (const float*)d_in[1];
    const float* gamp   = (const float*)d_in[2];
    const float* oamp   = (const float*)d_in[3];
    const float* noise  = (const float*)d_in[4];
    float* out = (float*)d_out;

    float* ws = (float*)d_ws;
    float* noise_out = ws;
    float* res = ws + (size_t)B_EVENTS * N_SAMPLES;
    float* rW  = res + B_EVENTS * 8 * 128;

    prep_kernel<<<B_EVENTS, 128, 0, stream>>>(packed, freqs, rW, res);
    fft_filter_kernel<<<B_EVENTS, 512, (2 * LDS_N + 16) * sizeof(float), stream>>>(
        noise, packed, gamp, noise_out);
    assemble_kernel<<<dim3(N_SAMPLES / 256, N_GROUPS), 256, 0, stream>>>(
        packed, rW, res, noise_out, oamp, out);
}

// Round 4
// 141.127 us; speedup vs baseline: 1.2873x; 1.0276x over previous
//
#include <hip/hip_runtime.h>
#include <math.h>

#define PCK_STRIDE 416
#define N_SAMPLES  32768
#define FFT_M      16384        // complex FFT size (real packing)
#define B_EVENTS   128
#define N_GROUPS   16
#define PI_F 3.14159265358979323846f
#define RT2H 0.70710678118654752f   // sqrt(2)/2

// LDS padded mapping: +4 floats per 32-block. Bank-checked: all r4 stages and
// the r8 register phase are <=2-way (free); pointwise pass is 4-way on its
// primary access. 8-blocks never cross a 32-boundary, so 8 consecutive
// elements stay contiguous and 16B-aligned (byte addr 144*tid+32*s).
#define MAP(i) ((i) + (((i) >> 5) << 2))
#define LDS_N  18432            // 16384 + 2048 pad

__device__ inline float filt_at(const float* __restrict__ f, int k) {
    if (k >= FFT_M) return 0.0f;
    float c = ((float)k + 0.5f) * (1.0f / 1024.0f) - 0.5f;
    c = fminf(fmaxf(c, 0.0f), 15.0f);
    int i0 = (int)floorf(c);
    int i1 = min(i0 + 1, 15);
    float w = c - (float)i0;
    return f[i0] * (1.0f - w) + f[i1] * w;
}

// ---------------- K1: softmax-f0, radians, decay scan ----------------
__global__ __launch_bounds__(128) void prep_kernel(
    const float* __restrict__ packed, const float* __restrict__ freqs,
    float* __restrict__ rW, float* __restrict__ res)
{
    const int b = blockIdx.x;
    const int t = threadIdx.x;
    __shared__ float sm[128];
    __shared__ float s_amp[128];
    const float* row = packed + b * PCK_STRIDE;
    float lv = row[t];
    s_amp[t] = row[256 + t] * 2.0f - 1.0f;
    sm[t] = lv; __syncthreads();
    for (int s = 64; s > 0; s >>= 1) { if (t < s) sm[t] = fmaxf(sm[t], sm[t + s]); __syncthreads(); }
    float mx = sm[0]; __syncthreads();
    float ex = __expf(lv - mx);
    sm[t] = ex; __syncthreads();
    for (int s = 64; s > 0; s >>= 1) { if (t < s) sm[t] += sm[t + s]; __syncthreads(); }
    float den = sm[0]; __syncthreads();
    sm[t] = ex * freqs[t]; __syncthreads();
    for (int s = 64; s > 0; s >>= 1) { if (t < s) sm[t] += sm[t + s]; __syncthreads(); }
    float num = sm[0];

    if (t < 8) {
        const float MIN_F0 = 40.0f / 11025.0f;
        const float F0_SPAN = 3000.0f / 11025.0f - 40.0f / 11025.0f;
        float f0s = num / den;
        float f0 = MIN_F0 + f0s * f0s * 11025.0f * F0_SPAN;
        float r = f0 * (float)(t + 1) * (PI_F / 11025.0f);
        if (r >= PI_F) r = 0.0f;
        rW[b * 8 + t] = r;
        float ha = row[384 + t];
        float hd = 0.5f + row[392 + t] * 0.5f;
        float cur = 0.0f;
        float* rr = res + (b * 8 + t) * 128;
        for (int f = 0; f < 128; ++f) {
            float c = fmaxf(cur + s_amp[f] * ha, 0.0f);
            rr[f] = c;
            cur = c * hd;
        }
    }
}

// ---------------- radix-4 LDS stages ----------------
template<int L>
__device__ inline void r4_dif_stage(float* re, float* im, int tid) {
    constexpr int q = L >> 2;
    constexpr float ang = -6.28318530717958647692f / (float)L;
    #pragma unroll
    for (int s = 0; s < 8; ++s) {
        int m = tid + (s << 9);
        int t = m & (q - 1);
        int i0 = ((m & ~(q - 1)) << 2) | t;
        int ia = MAP(i0), ib = MAP(i0 + q), ic = MAP(i0 + 2 * q), id = MAP(i0 + 3 * q);
        float ar = re[ia], ai = im[ia];
        float br = re[ib], bi = im[ib];
        float cr = re[ic], ci = im[ic];
        float dr = re[id], di = im[id];
        float s1, c1; __sincosf(ang * (float)t, &s1, &c1);
        float c2 = c1 * c1 - s1 * s1, s2 = 2.0f * c1 * s1;
        float c3 = c2 * c1 - s2 * s1, s3 = c2 * s1 + s2 * c1;
        float s0r = ar + cr, s0i = ai + ci;
        float t1r = br + dr, t1i = bi + di;
        float d0r = ar - cr, d0i = ai - ci;
        float d1r = br - dr, d1i = bi - di;
        re[ia] = s0r + t1r; im[ia] = s0i + t1i;
        float er = s0r - t1r, ei = s0i - t1i;
        re[ib] = er * c2 - ei * s2; im[ib] = er * s2 + ei * c2;
        float fr = d0r + d1i, fi = d0i - d1r;   // (a-c) - i(b-d)
        re[ic] = fr * c1 - fi * s1; im[ic] = fr * s1 + fi * c1;
        float gr = d0r - d1i, gi = d0i + d1r;   // (a-c) + i(b-d)
        re[id] = gr * c3 - gi * s3; im[id] = gr * s3 + gi * c3;
    }
    __syncthreads();
}

template<int L>
__device__ inline void r4_dit_stage(float* re, float* im, int tid) {
    constexpr int q = L >> 2;
    constexpr float ang = 6.28318530717958647692f / (float)L;
    #pragma unroll
    for (int s = 0; s < 8; ++s) {
        int m = tid + (s << 9);
        int t = m & (q - 1);
        int i0 = ((m & ~(q - 1)) << 2) | t;
        int ia = MAP(i0), ib = MAP(i0 + q), ic = MAP(i0 + 2 * q), id = MAP(i0 + 3 * q);
        float ar = re[ia], ai = im[ia];
        float br = re[ib], bi = im[ib];
        float cr = re[ic], ci = im[ic];
        float dr = re[id], di = im[id];
        float s1, c1; __sincosf(ang * (float)t, &s1, &c1);
        float c2 = c1 * c1 - s1 * s1, s2 = 2.0f * c1 * s1;
        float tbr = br * c2 - bi * s2, tbi = br * s2 + bi * c2;
        float tdr = dr * c2 - di * s2, tdi = dr * s2 + di * c2;
        float B0r = ar + tbr, B0i = ai + tbi;
        float B1r = ar - tbr, B1i = ai - tbi;
        float B2r = cr + tdr, B2i = ci + tdi;
        float B3r = cr - tdr, B3i = ci - tdi;
        float t0r = B2r * c1 - B2i * s1, t0i = B2r * s1 + B2i * c1;
        float t1r = -B3r * s1 - B3i * c1, t1i = B3r * c1 - B3i * s1;  // B3*(i*w1)
        re[ia] = B0r + t0r; im[ia] = B0i + t0i;
        re[ib] = B1r + t1r; im[ib] = B1i + t1i;
        re[ic] = B0r - t0r; im[ic] = B0i - t0i;
        re[id] = B1r - t1r; im[id] = B1i - t1i;
    }
    __syncthreads();
}

// ---------------- K2: 16384-pt complex FFT filter ----------------
// Register phase is radix-8 with EXPLICIT SCALARS (no local arrays ->
// nothing can be demoted to scratch; this was the R2/R3 spill source).
__global__ __launch_bounds__(512) void fft_filter_kernel(
    const float* __restrict__ noise, const float* __restrict__ packed,
    const float* __restrict__ gamp, float* __restrict__ noise_out)
{
    extern __shared__ float smem[];
    float* re = smem;
    float* im = smem + LDS_N;
    float* filt = smem + 2 * LDS_N;
    const int b = blockIdx.x;
    const int tid = threadIdx.x;
    const float g = gamp[0];

    // --- load + fused r2 DIF (half=8192) ---
    const float2* nz = (const float2*)(noise + (size_t)b * N_SAMPLES);
    #pragma unroll
    for (int s = 0; s < 16; ++s) {
        int j = tid + (s << 9);
        float2 v0 = nz[j];
        float2 v1 = nz[j + 8192];
        float ur = v0.x * g, ui = v0.y * g;
        float wr = v1.x * g, wi = v1.y * g;
        float s1, c1; __sincosf((-PI_F / 8192.0f) * (float)j, &s1, &c1);
        int a0 = MAP(j), a1 = MAP(j + 8192);
        re[a0] = ur + wr; im[a0] = ui + wi;
        float dr = ur - wr, di = ui - wi;
        re[a1] = dr * c1 - di * s1;
        im[a1] = dr * s1 + di * c1;
    }
    if (tid < 16) filt[tid] = packed[b * PCK_STRIDE + 400 + tid];
    __syncthreads();

    // --- radix-4 DIF stages ---
    r4_dif_stage<8192>(re, im, tid);
    r4_dif_stage<2048>(re, im, tid);
    r4_dif_stage<512>(re, im, tid);
    r4_dif_stage<128>(re, im, tid);
    r4_dif_stage<32>(re, im, tid);

    // --- register radix-8 DIF (half=4,2,1), scalar vars, float4 LDS I/O ---
    #pragma unroll
    for (int s = 0; s < 4; ++s) {
        int a = 36 * tid + 8 * s;          // MAP(8*(4*tid+s))
        float4 r0 = *(const float4*)(re + a);
        float4 r1 = *(const float4*)(re + a + 4);
        float4 q0 = *(const float4*)(im + a);
        float4 q1 = *(const float4*)(im + a + 4);
        // half=4
        float t0r = r0.x + r1.x, t0i = q0.x + q1.x;
        float u0r = r0.x - r1.x, u0i = q0.x - q1.x;
        float d1r = r0.y - r1.y, d1i = q0.y - q1.y;
        float t1r = r0.y + r1.y, t1i = q0.y + q1.y;
        float u1r = RT2H * (d1r + d1i), u1i = RT2H * (d1i - d1r);   // *(c-ci)
        float t2r = r0.z + r1.z, t2i = q0.z + q1.z;
        float d2r = r0.z - r1.z, d2i = q0.z - q1.z;
        float u2r = d2i, u2i = -d2r;                                  // *(-i)
        float t3r = r0.w + r1.w, t3i = q0.w + q1.w;
        float d3r = r0.w - r1.w, d3i = q0.w - q1.w;
        float u3r = RT2H * (d3i - d3r), u3i = -RT2H * (d3r + d3i);  // *(-c-ci)
        // half=2
        float A0r = t0r + t2r, A0i = t0i + t2i;
        float A2r = t0r - t2r, A2i = t0i - t2i;
        float A1r = t1r + t3r, A1i = t1i + t3i;
        float e3r = t1r - t3r, e3i = t1i - t3i;
        float A3r = e3i, A3i = -e3r;                                  // *(-i)
        float B0r = u0r + u2r, B0i = u0i + u2i;
        float B2r = u0r - u2r, B2i = u0i - u2i;
        float B1r = u1r + u3r, B1i = u1i + u3i;
        float f3r = u1r - u3r, f3i = u1i - u3i;
        float B3r = f3i, B3i = -f3r;
        // half=1
        r0.x = A0r + A1r; q0.x = A0i + A1i;
        r0.y = A0r - A1r; q0.y = A0i - A1i;
        r0.z = A2r + A3r; q0.z = A2i + A3i;
        r0.w = A2r - A3r; q0.w = A2i - A3i;
        r1.x = B0r + B1r; q1.x = B0i + B1i;
        r1.y = B0r - B1r; q1.y = B0i - B1i;
        r1.z = B2r + B3r; q1.z = B2i + B3i;
        r1.w = B2r - B3r; q1.w = B2i - B3i;
        *(float4*)(re + a) = r0; *(float4*)(re + a + 4) = r1;
        *(float4*)(im + a) = q0; *(float4*)(im + a + 4) = q1;
    }
    __syncthreads();

    // --- pointwise untangle * H * retangle, bitrev domain ---
    const float invM = 1.0f / (float)FFT_M;
    #pragma unroll
    for (int s = 0; s < 16; ++s) {
        int jj = (tid + (s << 9)) << 1;       // even position
        if (jj == 0) {
            int p0 = MAP(0);
            float z0r = re[p0], z0i = im[p0];
            float y = 0.5f * filt_at(filt, 0) * (z0r + z0i) * invM;
            re[p0] = y; im[p0] = y;
            int p1 = MAP(1);                  // k=8192 self-pair at brev(8192)=1
            float H = filt_at(filt, 8192) * invM;
            re[p1] *= H; im[p1] *= H;
        } else {
            int k = (int)(__brev((unsigned)jj) >> 18);     // k in [1,8192)
            int kq = FFT_M - k;
            int pk = MAP(jj);
            int pq = MAP((int)(__brev((unsigned)kq) >> 18));
            float zkr = re[pk], zki = im[pk];
            float zqr = re[pq], zqi = im[pq];
            float Er = 0.5f * (zkr + zqr), Ei = 0.5f * (zki - zqi);
            float Or = 0.5f * (zki + zqi), Oi = 0.5f * (zqr - zkr);
            float th = (float)k * (PI_F / (float)FFT_M);
            float s1, c1; __sincosf(th, &s1, &c1);
            float ts = -s1;
            float tOr = c1 * Or - ts * Oi;
            float tOi = c1 * Oi + ts * Or;
            float Hk = filt_at(filt, k);
            float Hq = filt_at(filt, kq);
            float Ykr = Hk * (Er + tOr), Yki = Hk * (Ei + tOi);
            float Cr  = Hq * (Er - tOr), Ci  = Hq * (Ei - tOi);
            float Ar = 0.5f * (Ykr + Cr), Ai = 0.5f * (Yki + Ci);
            float Br = 0.5f * (Ykr - Cr), Bi = 0.5f * (Yki - Ci);
            re[pk] = (Ar + ts * Br - c1 * Bi) * invM;
            im[pk] = (Ai + c1 * Br + ts * Bi) * invM;
            re[pq] = (Ar + c1 * Bi - ts * Br) * invM;
            im[pq] = (-Ai + c1 * Br + ts * Bi) * invM;
        }
    }
    __syncthreads();

    // --- register radix-8 DIT (half=1,2,4), scalar vars ---
    #pragma unroll
    for (int s = 0; s < 4; ++s) {
        int a = 36 * tid + 8 * s;
        float4 r0 = *(const float4*)(re + a);
        float4 r1 = *(const float4*)(re + a + 4);
        float4 q0 = *(const float4*)(im + a);
        float4 q1 = *(const float4*)(im + a + 4);
        // half=1
        float A0r = r0.x + r0.y, A0i = q0.x + q0.y;
        float A1r = r0.x - r0.y, A1i = q0.x - q0.y;
        float A2r = r0.z + r0.w, A2i = q0.z + q0.w;
        float A3r = r0.z - r0.w, A3i = q0.z - q0.w;
        float B0r = r1.x + r1.y, B0i = q1.x + q1.y;
        float B1r = r1.x - r1.y, B1i = q1.x - q1.y;
        float B2r = r1.z + r1.w, B2i = q1.z + q1.w;
        float B3r = r1.z - r1.w, B3i = q1.z - q1.w;
        // half=2 ; twiddle on odd: *(+i)
        float t0r = A0r + A2r, t0i = A0i + A2i;
        float t2r = A0r - A2r, t2i = A0i - A2i;
        float w3r = -A3i, w3i = A3r;
        float t1r = A1r + w3r, t1i = A1i + w3i;
        float t3r = A1r - w3r, t3i = A1i - w3i;
        float u0r = B0r + B2r, u0i = B0i + B2i;
        float u2r = B0r - B2r, u2i = B0i - B2i;
        float x3r = -B3i, x3i = B3r;
        float u1r = B1r + x3r, u1i = B1i + x3i;
        float u3r = B1r - x3r, u3i = B1i - x3i;
        // half=4 ; twiddles 1, c(1+i), +i, c(-1+i)
        float w1r = RT2H * (u1r - u1i), w1i = RT2H * (u1r + u1i);
        float w2r = -u2i,               w2i = u2r;
        float w5r = RT2H * (-u3r - u3i), w5i = RT2H * (u3r - u3i);
        r0.x = t0r + u0r; q0.x = t0i + u0i;
        r1.x = t0r - u0r; q1.x = t0i - u0i;
        r0.y = t1r + w1r; q0.y = t1i + w1i;
        r1.y = t1r - w1r; q1.y = t1i - w1i;
        r0.z = t2r + w2r; q0.z = t2i + w2i;
        r1.z = t2r - w2r; q1.z = t2i - w2i;
        r0.w = t3r + w5r; q0.w = t3i + w5i;
        r1.w = t3r - w5r; q1.w = t3i - w5i;
        *(float4*)(re + a) = r0; *(float4*)(re + a + 4) = r1;
        *(float4*)(im + a) = q0; *(float4*)(im + a + 4) = q1;
    }
    __syncthreads();

    // --- radix-4 DIT stages ---
    r4_dit_stage<32>(re, im, tid);
    r4_dit_stage<128>(re, im, tid);
    r4_dit_stage<512>(re, im, tid);
    r4_dit_stage<2048>(re, im, tid);
    r4_dit_stage<8192>(re, im, tid);

    // --- fused final r2 DIT (half=8192) + store ---
    float2* oz = (float2*)(noise_out + (size_t)b * N_SAMPLES);
    #pragma unroll
    for (int s = 0; s < 16; ++s) {
        int j = tid + (s << 9);
        int a0 = MAP(j), a1 = MAP(j + 8192);
        float ur = re[a0], ui = im[a0];
        float xr = re[a1], xi = im[a1];
        float s1, c1; __sincosf((PI_F / 8192.0f) * (float)j, &s1, &c1);
        float wr = xr * c1 - xi * s1, wi = xr * s1 + xi * c1;
        oz[j] = make_float2(ur + wr, ui + wi);
        oz[j + 8192] = make_float2(ur - wr, ui - wi);
    }
}

// ---------------- K3: gate noise, add harmonic bank, sum 8 events ----------------
__global__ __launch_bounds__(256) void assemble_kernel(
    const float* __restrict__ packed, const float* __restrict__ rW,
    const float* __restrict__ res, const float* __restrict__ noise_out,
    const float* __restrict__ oamp, float* __restrict__ out)
{
    const int g = blockIdx.y;
    const int chunk = blockIdx.x;
    const int tid = threadIdx.x;
    const int n = chunk * 256 + tid;
    const int fb = chunk - 1;

    __shared__ float s_res[8][8][3];
    __shared__ float s_ampf[8][3];
    __shared__ float s_r[8][8];
    if (tid < 192) {
        int e = tid / 24, rem = tid % 24, h = rem / 3, j = rem % 3;
        int f = min(max(fb + j, 0), 127);
        s_res[e][h][j] = res[((g * 8 + e) * 8 + h) * 128 + f];
    }
    if (tid < 24) {
        int e = tid / 3, j = tid % 3;
        int f = min(max(fb + j, 0), 127);
        s_ampf[e][j] = packed[(g * 8 + e) * PCK_STRIDE + 256 + f] * 2.0f - 1.0f;
    }
    if (tid >= 192 && tid < 256) {
        int u = tid - 192;
        s_r[u / 8][u % 8] = rW[g * 64 + u];
    }
    __syncthreads();

    float coords = ((float)n + 0.5f) * (1.0f / 256.0f) - 0.5f;
    coords = fminf(fmaxf(coords, 0.0f), 127.0f);
    int i0 = (int)floorf(coords);
    float w = coords - (float)i0;
    int j0 = i0 - fb;
    float osc50 = oamp[0];
    float pn = (float)(n + 1);
    float wm = 1.0f - w;

    float acc = 0.0f;
    for (int e = 0; e < 8; ++e) {
        int b = g * 8 + e;
        float nv = noise_out[(size_t)b * N_SAMPLES + n];
        float av = s_ampf[e][j0] * wm + s_ampf[e][j0 + 1] * w;
        float gate = (av >= 0.0f) ? av : 0.2f * av;
        acc += nv * gate;
        for (int h = 0; h < 8; ++h) {
            float rsv = s_res[e][h][j0] * wm + s_res[e][h][j0 + 1] * w;
            acc += rsv * osc50 * __sinf(pn * s_r[e][h]);
        }
    }
    out[(size_t)g * N_SAMPLES + n] = acc;
}

extern "C" void kernel_launch(void* const* d_in, const int* in_sizes, int n_in,
                              void* d_out, int out_size, void* d_ws, size_t ws_size,
                              hipStream_t stream) {
    const float* packed = (const float*)d_in[0];
    const float* freqs  = (const float*)d_in[1];
    const float* gamp   = (const float*)d_in[2];
    const float* oamp   = (const float*)d_in[3];
    const float* noise  = (const float*)d_in[4];
    float* out = (float*)d_out;

    float* ws = (float*)d_ws;
    float* noise_out = ws;
    float* res = ws + (size_t)B_EVENTS * N_SAMPLES;
    float* rW  = res + B_EVENTS * 8 * 128;

    prep_kernel<<<B_EVENTS, 128, 0, stream>>>(packed, freqs, rW, res);
    fft_filter_kernel<<<B_EVENTS, 512, (2 * LDS_N + 16) * sizeof(float), stream>>>(
        noise, packed, gamp, noise_out);
    assemble_kernel<<<dim3(N_SAMPLES / 256, N_GROUPS), 256, 0, stream>>>(
        packed, rW, res, noise_out, oamp, out);
}

// Round 5
// 120.414 us; speedup vs baseline: 1.5088x; 1.1720x over previous
//
#include <hip/hip_runtime.h>
#include <math.h>

#define PCK_STRIDE 416
#define N_SAMPLES  32768
#define FFT_M      16384        // complex FFT size (real packing)
#define B_EVENTS   128
#define N_GROUPS   16
#define PI_F 3.14159265358979323846f
#define RT2H 0.70710678118654752f   // sqrt(2)/2

// LDS padded mapping: +4 floats per 32-block (keeps 8-blocks contiguous and
// 16B-aligned; all r4/r8 accesses <=2-way bank aliasing).
#define MAP(i) ((i) + (((i) >> 5) << 2))
#define LDS_N  18432            // 16384 + 2048 pad

__device__ inline float filt_at(const float* __restrict__ f, int k) {
    if (k >= FFT_M) return 0.0f;
    float c = ((float)k + 0.5f) * (1.0f / 1024.0f) - 0.5f;
    c = fminf(fmaxf(c, 0.0f), 15.0f);
    int i0 = (int)floorf(c);
    int i1 = min(i0 + 1, 15);
    float w = c - (float)i0;
    return f[i0] * (1.0f - w) + f[i1] * w;
}

// ---------------- K1: softmax-f0, radians, decay scan ----------------
__global__ __launch_bounds__(128) void prep_kernel(
    const float* __restrict__ packed, const float* __restrict__ freqs,
    float* __restrict__ rW, float* __restrict__ res)
{
    const int b = blockIdx.x;
    const int t = threadIdx.x;
    __shared__ float sm[128];
    __shared__ float s_amp[128];
    const float* row = packed + b * PCK_STRIDE;
    float lv = row[t];
    s_amp[t] = row[256 + t] * 2.0f - 1.0f;
    sm[t] = lv; __syncthreads();
    for (int s = 64; s > 0; s >>= 1) { if (t < s) sm[t] = fmaxf(sm[t], sm[t + s]); __syncthreads(); }
    float mx = sm[0]; __syncthreads();
    float ex = __expf(lv - mx);
    sm[t] = ex; __syncthreads();
    for (int s = 64; s > 0; s >>= 1) { if (t < s) sm[t] += sm[t + s]; __syncthreads(); }
    float den = sm[0]; __syncthreads();
    sm[t] = ex * freqs[t]; __syncthreads();
    for (int s = 64; s > 0; s >>= 1) { if (t < s) sm[t] += sm[t + s]; __syncthreads(); }
    float num = sm[0];

    if (t < 8) {
        const float MIN_F0 = 40.0f / 11025.0f;
        const float F0_SPAN = 3000.0f / 11025.0f - 40.0f / 11025.0f;
        float f0s = num / den;
        float f0 = MIN_F0 + f0s * f0s * 11025.0f * F0_SPAN;
        float r = f0 * (float)(t + 1) * (PI_F / 11025.0f);
        if (r >= PI_F) r = 0.0f;
        rW[b * 8 + t] = r;
        float ha = row[384 + t];
        float hd = 0.5f + row[392 + t] * 0.5f;
        float cur = 0.0f;
        float* rr = res + (b * 8 + t) * 128;
        for (int f = 0; f < 128; ++f) {
            float c = fmaxf(cur + s_amp[f] * ha, 0.0f);
            rr[f] = c;
            cur = c * hd;
        }
    }
}

// ---------------- radix-4 LDS stages ----------------
// unroll 2: cap live range (~50 VGPR) so the allocator never spills.
template<int L>
__device__ inline void r4_dif_stage(float* re, float* im, int tid) {
    constexpr int q = L >> 2;
    constexpr float ang = -6.28318530717958647692f / (float)L;
    #pragma unroll 2
    for (int s = 0; s < 8; ++s) {
        int m = tid + (s << 9);
        int t = m & (q - 1);
        int i0 = ((m & ~(q - 1)) << 2) | t;
        int ia = MAP(i0), ib = MAP(i0 + q), ic = MAP(i0 + 2 * q), id = MAP(i0 + 3 * q);
        float ar = re[ia], ai = im[ia];
        float br = re[ib], bi = im[ib];
        float cr = re[ic], ci = im[ic];
        float dr = re[id], di = im[id];
        float s1, c1; __sincosf(ang * (float)t, &s1, &c1);
        float c2 = c1 * c1 - s1 * s1, s2 = 2.0f * c1 * s1;
        float c3 = c2 * c1 - s2 * s1, s3 = c2 * s1 + s2 * c1;
        float s0r = ar + cr, s0i = ai + ci;
        float t1r = br + dr, t1i = bi + di;
        float d0r = ar - cr, d0i = ai - ci;
        float d1r = br - dr, d1i = bi - di;
        re[ia] = s0r + t1r; im[ia] = s0i + t1i;
        float er = s0r - t1r, ei = s0i - t1i;
        re[ib] = er * c2 - ei * s2; im[ib] = er * s2 + ei * c2;
        float fr = d0r + d1i, fi = d0i - d1r;   // (a-c) - i(b-d)
        re[ic] = fr * c1 - fi * s1; im[ic] = fr * s1 + fi * c1;
        float gr = d0r - d1i, gi = d0i + d1r;   // (a-c) + i(b-d)
        re[id] = gr * c3 - gi * s3; im[id] = gr * s3 + gi * c3;
    }
    __syncthreads();
}

template<int L>
__device__ inline void r4_dit_stage(float* re, float* im, int tid) {
    constexpr int q = L >> 2;
    constexpr float ang = 6.28318530717958647692f / (float)L;
    #pragma unroll 2
    for (int s = 0; s < 8; ++s) {
        int m = tid + (s << 9);
        int t = m & (q - 1);
        int i0 = ((m & ~(q - 1)) << 2) | t;
        int ia = MAP(i0), ib = MAP(i0 + q), ic = MAP(i0 + 2 * q), id = MAP(i0 + 3 * q);
        float ar = re[ia], ai = im[ia];
        float br = re[ib], bi = im[ib];
        float cr = re[ic], ci = im[ic];
        float dr = re[id], di = im[id];
        float s1, c1; __sincosf(ang * (float)t, &s1, &c1);
        float c2 = c1 * c1 - s1 * s1, s2 = 2.0f * c1 * s1;
        float tbr = br * c2 - bi * s2, tbi = br * s2 + bi * c2;
        float tdr = dr * c2 - di * s2, tdi = dr * s2 + di * c2;
        float B0r = ar + tbr, B0i = ai + tbi;
        float B1r = ar - tbr, B1i = ai - tbi;
        float B2r = cr + tdr, B2i = ci + tdi;
        float B3r = cr - tdr, B3i = ci - tdi;
        float t0r = B2r * c1 - B2i * s1, t0i = B2r * s1 + B2i * c1;
        float t1r = -B3r * s1 - B3i * c1, t1i = B3r * c1 - B3i * s1;  // B3*(i*w1)
        re[ia] = B0r + t0r; im[ia] = B0i + t0i;
        re[ib] = B1r + t1r; im[ib] = B1i + t1i;
        re[ic] = B0r - t0r; im[ic] = B0i - t0i;
        re[id] = B1r - t1r; im[id] = B1i - t1i;
    }
    __syncthreads();
}

// ---------------- K2: 16384-pt complex FFT filter ----------------
__global__ __launch_bounds__(512)
__attribute__((amdgpu_waves_per_eu(2)))
void fft_filter_kernel(
    const float* __restrict__ noise, const float* __restrict__ packed,
    const float* __restrict__ gamp, float* __restrict__ noise_out)
{
    extern __shared__ float smem[];
    float* re = smem;
    float* im = smem + LDS_N;
    float* filt = smem + 2 * LDS_N;
    const int b = blockIdx.x;
    const int tid = threadIdx.x;
    const float g = gamp[0];

    // --- load + fused r2 DIF (half=8192) ---
    const float2* nz = (const float2*)(noise + (size_t)b * N_SAMPLES);
    #pragma unroll 4
    for (int s = 0; s < 16; ++s) {
        int j = tid + (s << 9);
        float2 v0 = nz[j];
        float2 v1 = nz[j + 8192];
        float ur = v0.x * g, ui = v0.y * g;
        float wr = v1.x * g, wi = v1.y * g;
        float s1, c1; __sincosf((-PI_F / 8192.0f) * (float)j, &s1, &c1);
        int a0 = MAP(j), a1 = MAP(j + 8192);
        re[a0] = ur + wr; im[a0] = ui + wi;
        float dr = ur - wr, di = ui - wi;
        re[a1] = dr * c1 - di * s1;
        im[a1] = dr * s1 + di * c1;
    }
    if (tid < 16) filt[tid] = packed[b * PCK_STRIDE + 400 + tid];
    __syncthreads();

    // --- radix-4 DIF stages ---
    r4_dif_stage<8192>(re, im, tid);
    r4_dif_stage<2048>(re, im, tid);
    r4_dif_stage<512>(re, im, tid);
    r4_dif_stage<128>(re, im, tid);
    r4_dif_stage<32>(re, im, tid);

    // --- register radix-8 DIF (half=4,2,1), scalar vars, float4 LDS I/O ---
    #pragma unroll 2
    for (int s = 0; s < 4; ++s) {
        int a = 36 * tid + 8 * s;          // MAP(8*(4*tid+s))
        float4 r0 = *(const float4*)(re + a);
        float4 r1 = *(const float4*)(re + a + 4);
        float4 q0 = *(const float4*)(im + a);
        float4 q1 = *(const float4*)(im + a + 4);
        // half=4
        float t0r = r0.x + r1.x, t0i = q0.x + q1.x;
        float u0r = r0.x - r1.x, u0i = q0.x - q1.x;
        float d1r = r0.y - r1.y, d1i = q0.y - q1.y;
        float t1r = r0.y + r1.y, t1i = q0.y + q1.y;
        float u1r = RT2H * (d1r + d1i), u1i = RT2H * (d1i - d1r);   // *(c-ci)
        float t2r = r0.z + r1.z, t2i = q0.z + q1.z;
        float d2r = r0.z - r1.z, d2i = q0.z - q1.z;
        float u2r = d2i, u2i = -d2r;                                  // *(-i)
        float t3r = r0.w + r1.w, t3i = q0.w + q1.w;
        float d3r = r0.w - r1.w, d3i = q0.w - q1.w;
        float u3r = RT2H * (d3i - d3r), u3i = -RT2H * (d3r + d3i);  // *(-c-ci)
        // half=2
        float A0r = t0r + t2r, A0i = t0i + t2i;
        float A2r = t0r - t2r, A2i = t0i - t2i;
        float A1r = t1r + t3r, A1i = t1i + t3i;
        float e3r = t1r - t3r, e3i = t1i - t3i;
        float A3r = e3i, A3i = -e3r;                                  // *(-i)
        float B0r = u0r + u2r, B0i = u0i + u2i;
        float B2r = u0r - u2r, B2i = u0i - u2i;
        float B1r = u1r + u3r, B1i = u1i + u3i;
        float f3r = u1r - u3r, f3i = u1i - u3i;
        float B3r = f3i, B3i = -f3r;
        // half=1
        r0.x = A0r + A1r; q0.x = A0i + A1i;
        r0.y = A0r - A1r; q0.y = A0i - A1i;
        r0.z = A2r + A3r; q0.z = A2i + A3i;
        r0.w = A2r - A3r; q0.w = A2i - A3i;
        r1.x = B0r + B1r; q1.x = B0i + B1i;
        r1.y = B0r - B1r; q1.y = B0i - B1i;
        r1.z = B2r + B3r; q1.z = B2i + B3i;
        r1.w = B2r - B3r; q1.w = B2i - B3i;
        *(float4*)(re + a) = r0; *(float4*)(re + a + 4) = r1;
        *(float4*)(im + a) = q0; *(float4*)(im + a + 4) = q1;
    }
    __syncthreads();

    // --- pointwise untangle * H * retangle, bitrev domain ---
    const float invM = 1.0f / (float)FFT_M;
    #pragma unroll 2
    for (int s = 0; s < 16; ++s) {
        int jj = (tid + (s << 9)) << 1;       // even position
        if (jj == 0) {
            int p0 = MAP(0);
            float z0r = re[p0], z0i = im[p0];
            float y = 0.5f * filt_at(filt, 0) * (z0r + z0i) * invM;
            re[p0] = y; im[p0] = y;
            int p1 = MAP(1);                  // k=8192 self-pair at brev(8192)=1
            float H = filt_at(filt, 8192) * invM;
            re[p1] *= H; im[p1] *= H;
        } else {
            int k = (int)(__brev((unsigned)jj) >> 18);     // k in [1,8192)
            int kq = FFT_M - k;
            int pk = MAP(jj);
            int pq = MAP((int)(__brev((unsigned)kq) >> 18));
            float zkr = re[pk], zki = im[pk];
            float zqr = re[pq], zqi = im[pq];
            float Er = 0.5f * (zkr + zqr), Ei = 0.5f * (zki - zqi);
            float Or = 0.5f * (zki + zqi), Oi = 0.5f * (zqr - zkr);
            float th = (float)k * (PI_F / (float)FFT_M);
            float s1, c1; __sincosf(th, &s1, &c1);
            float ts = -s1;
            float tOr = c1 * Or - ts * Oi;
            float tOi = c1 * Oi + ts * Or;
            float Hk = filt_at(filt, k);
            float Hq = filt_at(filt, kq);
            float Ykr = Hk * (Er + tOr), Yki = Hk * (Ei + tOi);
            float Cr  = Hq * (Er - tOr), Ci  = Hq * (Ei - tOi);
            float Ar = 0.5f * (Ykr + Cr), Ai = 0.5f * (Yki + Ci);
            float Br = 0.5f * (Ykr - Cr), Bi = 0.5f * (Yki - Ci);
            re[pk] = (Ar + ts * Br - c1 * Bi) * invM;
            im[pk] = (Ai + c1 * Br + ts * Bi) * invM;
            re[pq] = (Ar + c1 * Bi - ts * Br) * invM;
            im[pq] = (-Ai + c1 * Br + ts * Bi) * invM;
        }
    }
    __syncthreads();

    // --- register radix-8 DIT (half=1,2,4), scalar vars ---
    #pragma unroll 2
    for (int s = 0; s < 4; ++s) {
        int a = 36 * tid + 8 * s;
        float4 r0 = *(const float4*)(re + a);
        float4 r1 = *(const float4*)(re + a + 4);
        float4 q0 = *(const float4*)(im + a);
        float4 q1 = *(const float4*)(im + a + 4);
        // half=1
        float A0r = r0.x + r0.y, A0i = q0.x + q0.y;
        float A1r = r0.x - r0.y, A1i = q0.x - q0.y;
        float A2r = r0.z + r0.w, A2i = q0.z + q0.w;
        float A3r = r0.z - r0.w, A3i = q0.z - q0.w;
        float B0r = r1.x + r1.y, B0i = q1.x + q1.y;
        float B1r = r1.x - r1.y, B1i = q1.x - q1.y;
        float B2r = r1.z + r1.w, B2i = q1.z + q1.w;
        float B3r = r1.z - r1.w, B3i = q1.z - q1.w;
        // half=2 ; twiddle on odd: *(+i)
        float t0r = A0r + A2r, t0i = A0i + A2i;
        float t2r = A0r - A2r, t2i = A0i - A2i;
        float w3r = -A3i, w3i = A3r;
        float t1r = A1r + w3r, t1i = A1i + w3i;
        float t3r = A1r - w3r, t3i = A1i - w3i;
        float u0r = B0r + B2r, u0i = B0i + B2i;
        float u2r = B0r - B2r, u2i = B0i - B2i;
        float x3r = -B3i, x3i = B3r;
        float u1r = B1r + x3r, u1i = B1i + x3i;
        float u3r = B1r - x3r, u3i = B1i - x3i;
        // half=4 ; twiddles 1, c(1+i), +i, c(-1+i)
        float w1r = RT2H * (u1r - u1i), w1i = RT2H * (u1r + u1i);
        float w2r = -u2i,               w2i = u2r;
        float w5r = RT2H * (-u3r - u3i), w5i = RT2H * (u3r - u3i);
        r0.x = t0r + u0r; q0.x = t0i + u0i;
        r1.x = t0r - u0r; q1.x = t0i - u0i;
        r0.y = t1r + w1r; q0.y = t1i + w1i;
        r1.y = t1r - w1r; q1.y = t1i - w1i;
        r0.z = t2r + w2r; q0.z = t2i + w2i;
        r1.z = t2r - w2r; q1.z = t2i - w2i;
        r0.w = t3r + w5r; q0.w = t3i + w5i;
        r1.w = t3r - w5r; q1.w = t3i - w5i;
        *(float4*)(re + a) = r0; *(float4*)(re + a + 4) = r1;
        *(float4*)(im + a) = q0; *(float4*)(im + a + 4) = q1;
    }
    __syncthreads();

    // --- radix-4 DIT stages ---
    r4_dit_stage<32>(re, im, tid);
    r4_dit_stage<128>(re, im, tid);
    r4_dit_stage<512>(re, im, tid);
    r4_dit_stage<2048>(re, im, tid);
    r4_dit_stage<8192>(re, im, tid);

    // --- fused final r2 DIT (half=8192) + store ---
    float2* oz = (float2*)(noise_out + (size_t)b * N_SAMPLES);
    #pragma unroll 4
    for (int s = 0; s < 16; ++s) {
        int j = tid + (s << 9);
        int a0 = MAP(j), a1 = MAP(j + 8192);
        float ur = re[a0], ui = im[a0];
        float xr = re[a1], xi = im[a1];
        float s1, c1; __sincosf((PI_F / 8192.0f) * (float)j, &s1, &c1);
        float wr = xr * c1 - xi * s1, wi = xr * s1 + xi * c1;
        oz[j] = make_float2(ur + wr, ui + wi);
        oz[j + 8192] = make_float2(ur - wr, ui - wi);
    }
}

// ---------------- K3: gate noise, add harmonic bank, sum 8 events ----------------
// Chebyshev: r_h = h*r_1, so sin((n+1)*r_h) = U-recurrence from one sincos.
__global__ __launch_bounds__(256) void assemble_kernel(
    const float* __restrict__ packed, const float* __restrict__ rW,
    const float* __restrict__ res, const float* __restrict__ noise_out,
    const float* __restrict__ oamp, float* __restrict__ out)
{
    const int g = blockIdx.y;
    const int chunk = blockIdx.x;
    const int tid = threadIdx.x;
    const int n = chunk * 256 + tid;
    const int fb = chunk - 1;

    __shared__ float s_res[8][8][3];
    __shared__ float s_ampf[8][3];
    __shared__ float s_r[8][8];
    if (tid < 192) {
        int e = tid / 24, rem = tid % 24, h = rem / 3, j = rem % 3;
        int f = min(max(fb + j, 0), 127);
        s_res[e][h][j] = res[((g * 8 + e) * 8 + h) * 128 + f];
    }
    if (tid < 24) {
        int e = tid / 3, j = tid % 3;
        int f = min(max(fb + j, 0), 127);
        s_ampf[e][j] = packed[(g * 8 + e) * PCK_STRIDE + 256 + f] * 2.0f - 1.0f;
    }
    if (tid >= 192 && tid < 256) {
        int u = tid - 192;
        s_r[u / 8][u % 8] = rW[g * 64 + u];
    }
    __syncthreads();

    float coords = ((float)n + 0.5f) * (1.0f / 256.0f) - 0.5f;
    coords = fminf(fmaxf(coords, 0.0f), 127.0f);
    int i0 = (int)floorf(coords);
    float w = coords - (float)i0;
    int j0 = i0 - fb;
    float osc50 = oamp[0];
    float pn = (float)(n + 1);
    float wm = 1.0f - w;

    float acc = 0.0f;
    #pragma unroll
    for (int e = 0; e < 8; ++e) {
        int b = g * 8 + e;
        float nv = noise_out[(size_t)b * N_SAMPLES + n];
        float av = s_ampf[e][j0] * wm + s_ampf[e][j0 + 1] * w;
        float gate = (av >= 0.0f) ? av : 0.2f * av;
        acc += nv * gate;
        // sin((n+1)*h*r1) via Chebyshev recurrence; mask harmonics whose
        // radians were clamped to 0 (rW==0 -> osc term is sin(0)=0).
        float sn, cn; __sincosf(pn * s_r[e][0], &sn, &cn);
        float c2 = 2.0f * cn;
        float shm1 = 0.0f, sh = sn;
        #pragma unroll
        for (int h = 0; h < 8; ++h) {
            float rsv = s_res[e][h][j0] * wm + s_res[e][h][j0 + 1] * w;
            float sv = (s_r[e][h] != 0.0f) ? sh : 0.0f;
            acc += rsv * osc50 * sv;
            float nx = c2 * sh - shm1;
            shm1 = sh; sh = nx;
        }
    }
    out[(size_t)g * N_SAMPLES + n] = acc;
}

extern "C" void kernel_launch(void* const* d_in, const int* in_sizes, int n_in,
                              void* d_out, int out_size, void* d_ws, size_t ws_size,
                              hipStream_t stream) {
    const float* packed = (const float*)d_in[0];
    const float* freqs  = (const float*)d_in[1];
    const float* gamp   = (const float*)d_in[2];
    const float* oamp   = (const float*)d_in[3];
    const float* noise  = (const float*)d_in[4];
    float* out = (float*)d_out;

    float* ws = (float*)d_ws;
    float* noise_out = ws;
    float* res = ws + (size_t)B_EVENTS * N_SAMPLES;
    float* rW  = res + B_EVENTS * 8 * 128;

    prep_kernel<<<B_EVENTS, 128, 0, stream>>>(packed, freqs, rW, res);
    fft_filter_kernel<<<B_EVENTS, 512, (2 * LDS_N + 16) * sizeof(float), stream>>>(
        noise, packed, gamp, noise_out);
    assemble_kernel<<<dim3(N_SAMPLES / 256, N_GROUPS), 256, 0, stream>>>(
        packed, rW, res, noise_out, oamp, out);
}